// Round 7
// baseline (19907.272 us; speedup 1.0000x reference)
//
#include <hip/hip_runtime.h>

typedef unsigned short ushort;
typedef unsigned int uint32;
typedef unsigned long long ull;
typedef __attribute__((ext_vector_type(8))) short bf16x8;
typedef __attribute__((ext_vector_type(4))) float f32x4;

#define BATCH 16
#define TT 2048
#define HID 256

__device__ __forceinline__ ushort f2bf(float f) {
  union { float f; uint32 u; } v; v.f = f;
  uint32 r = v.u + 0x7FFFu + ((v.u >> 16) & 1u);
  return (ushort)(r >> 16);
}
__device__ __forceinline__ float bf2f(ushort u) {
  union { uint32 u; float f; } v; v.u = ((uint32)u) << 16; return v.f;
}
__device__ __forceinline__ float sigm(float x) { return 1.0f / (1.0f + __expf(-x)); }
__device__ __forceinline__ float tanh_fast(float x) { return 1.0f - 2.0f / (__expf(2.0f * x) + 1.0f); }

// ---------------- prep: x cast + l1 weight cast + bias sums ----------------
__global__ void prep_kernel(
    const float* __restrict__ x,
    const float* __restrict__ l1Wih_f, const float* __restrict__ l1Wih_b,
    const float* __restrict__ dbih_f, const float* __restrict__ dbhh_f,
    const float* __restrict__ dbih_b, const float* __restrict__ dbhh_b,
    const float* __restrict__ l0bih_f, const float* __restrict__ l0bhh_f,
    const float* __restrict__ l0bih_b, const float* __restrict__ l0bhh_b,
    const float* __restrict__ l1bih_f, const float* __restrict__ l1bhh_f,
    const float* __restrict__ l1bih_b, const float* __restrict__ l1bhh_b,
    ushort* __restrict__ xbf, ushort* __restrict__ wC,
    float* __restrict__ biasA, float* __restrict__ biasB, float* __restrict__ biasC)
{
  int g = blockIdx.x * blockDim.x + threadIdx.x;
  int str = gridDim.x * blockDim.x;
  for (int i = g; i < (BATCH * TT * 256) / 4; i += str) {
    float4 v = ((const float4*)x)[i];
    ushort4 o; o.x = f2bf(v.x); o.y = f2bf(v.y); o.z = f2bf(v.z); o.w = f2bf(v.w);
    ((ushort4*)xbf)[i] = o;
  }
  for (int i = g; i < 2048 * 512; i += str)
    wC[i] = f2bf(i < 1024 * 512 ? l1Wih_f[i] : l1Wih_b[i - 1024 * 512]);
  for (int i = g; i < 2048; i += str) {
    biasA[i] = i < 1024 ? dbih_f[i] + dbhh_f[i] : dbih_b[i - 1024] + dbhh_b[i - 1024];
    biasB[i] = i < 1024 ? l0bih_f[i] + l0bhh_f[i] : l0bih_b[i - 1024] + l0bhh_b[i - 1024];
    biasC[i] = i < 1024 ? l1bih_f[i] + l1bhh_f[i] : l1bih_b[i - 1024] + l1bhh_b[i - 1024];
  }
}

// ---------------- GEMM (l1 only): xp = A[32768,512] * B[2048,512]^T + bias ----------------
// Output layout (per dir): [b][t][pair u/2][gate 0..3][2 units]  (ushort)
__global__ __launch_bounds__(256) void gemm_xp(
    const ushort* __restrict__ A, const ushort* __restrict__ B, int K,
    const float* __restrict__ bias, ushort* __restrict__ xp)
{
  __shared__ __align__(16) ushort lA[128 * 64];
  __shared__ __align__(16) ushort lB[128 * 64];
  const int tid = threadIdx.x;
  const int lane = tid & 63, wv = tid >> 6;
  const int lo = lane & 15, hi = lane >> 4;
  const int wr = wv >> 1, wc = wv & 1;
  const int bm = blockIdx.y * 128, bn = blockIdx.x * 128;

  f32x4 acc[4][4] = {};

  const int nk = K >> 6;
  for (int kt = 0; kt < nk; ++kt) {
    uint4 ra[4], rb[4];
#pragma unroll
    for (int i = 0; i < 4; ++i) {
      int slot = i * 256 + tid;
      int r = slot >> 3, c8 = slot & 7;
      ra[i] = *(const uint4*)(A + (size_t)(bm + r) * K + kt * 64 + c8 * 8);
      rb[i] = *(const uint4*)(B + (size_t)(bn + r) * K + kt * 64 + c8 * 8);
    }
    __syncthreads();
#pragma unroll
    for (int i = 0; i < 4; ++i) {
      int slot = i * 256 + tid;
      int r = slot >> 3, c8 = slot & 7;
      int boff = r * 128 + ((c8 ^ (r & 7)) << 4);
      *(uint4*)((char*)lA + boff) = ra[i];
      *(uint4*)((char*)lB + boff) = rb[i];
    }
    __syncthreads();
#pragma unroll
    for (int kk = 0; kk < 2; ++kk) {
      bf16x8 fa[4], fb[4];
#pragma unroll
      for (int mt = 0; mt < 4; ++mt) {
        int r = wr * 64 + mt * 16 + lo;
        int c8 = kk * 4 + hi;
        fa[mt] = *(const bf16x8*)((const char*)lA + r * 128 + ((c8 ^ (r & 7)) << 4));
      }
#pragma unroll
      for (int nt = 0; nt < 4; ++nt) {
        int r = wc * 64 + nt * 16 + lo;
        int c8 = kk * 4 + hi;
        fb[nt] = *(const bf16x8*)((const char*)lB + r * 128 + ((c8 ^ (r & 7)) << 4));
      }
#pragma unroll
      for (int mt = 0; mt < 4; ++mt)
#pragma unroll
        for (int nt = 0; nt < 4; ++nt)
          acc[mt][nt] = __builtin_amdgcn_mfma_f32_16x16x32_bf16(fa[mt], fb[nt], acc[mt][nt], 0, 0, 0);
    }
  }
#pragma unroll
  for (int nt = 0; nt < 4; ++nt) {
    int n = bn + wc * 64 + nt * 16 + lo;
    float bv = bias[n];
    int dirn = n >> 10;
    int c = n & 1023;
    int gate = c >> 8;
    int u = c & 255;
    size_t base = (size_t)dirn * ((size_t)BATCH * TT * 1024) + (size_t)(u >> 1) * 8 + gate * 2;
#pragma unroll
    for (int mt = 0; mt < 4; ++mt) {
#pragma unroll
      for (int r = 0; r < 4; ++r) {
        float val = acc[mt][nt][r] + bv;
        uint32 h16 = f2bf(val);
        uint32 p16 = (uint32)__shfl_xor((int)h16, 1);
        if (!(lo & 1)) {
          int m = bm + wr * 64 + mt * 16 + hi * 4 + r;
          *(uint32*)(xp + base + (size_t)m * 1024) = h16 | (p16 << 16);
        }
      }
    }
  }
}

// ---------------- on-the-fly scan (dcg / l0): xg via in-kernel MFMA ----------------
// (round-6 structure + s_sleep poll backoff)
template <int MODE>
__device__ __forceinline__ void scan_fly(
    const ushort* __restrict__ xbf,
    const float* __restrict__ WihF, const float* __restrict__ WihB,
    const float* __restrict__ WhhF, const float* __restrict__ WhhB,
    const float* __restrict__ biasAll,
    const float* ldsCW, float cbias,
    ull* __restrict__ coefT,
    ull* __restrict__ hst_base,
    ushort* __restrict__ outBf,
    const int dir, const int w, const int tid)
{
  const int lane = tid & 63, wv = tid >> 6;
  const int lo = lane & 15, hi = lane >> 4;

  const float* Wih = dir ? WihB : WihF;
  const float* Whh = dir ? WhhB : WhhF;
  ull* hst = hst_base + dir * (2 * 2048);
  ull* coefD = coefT + (size_t)dir * TT * 16;

  const int unit = w * 64 + wv * 16 + lo;
  const int b0 = hi * 4;

  bf16x8 wih[4][8], whh[4][8];
#pragma unroll
  for (int gt = 0; gt < 4; ++gt) {
    const float* r1 = Wih + (size_t)(gt * HID + unit) * HID;
    const float* r2 = Whh + (size_t)(gt * HID + unit) * HID;
#pragma unroll
    for (int kt = 0; kt < 8; ++kt) {
      bf16x8 f1, f2;
#pragma unroll
      for (int j = 0; j < 8; ++j) {
        f1[j] = (short)f2bf(r1[kt * 32 + hi * 8 + j]);
        f2[j] = (short)f2bf(r2[kt * 32 + hi * 8 + j]);
      }
      wih[gt][kt] = f1; whh[gt][kt] = f2;
    }
  }
  float biasv[4];
#pragma unroll
  for (int gt = 0; gt < 4; ++gt) biasv[gt] = biasAll[dir * 1024 + gt * 256 + unit];

  float hprev[4] = {0, 0, 0, 0}, cprev[4] = {0, 0, 0, 0};
  float co[4] = {0, 0, 0, 0};

  uint4 xn[8];
  {
    const int t0 = dir ? (TT - 1) : 0;
    const ushort* p = xbf + ((size_t)lo * TT + t0) * 256 + hi * 8;
#pragma unroll
    for (int kt = 0; kt < 8; ++kt) xn[kt] = *(const uint4*)(p + kt * 32);
  }

  bf16x8 af[8];

  for (int s = 0; s < TT; ++s) {
    bf16x8 xa[8];
#pragma unroll
    for (int kt = 0; kt < 8; ++kt) {
      union { uint4 u; bf16x8 v; } t; t.u = xn[kt]; xa[kt] = t.v;
    }
    f32x4 acc[4];
#pragma unroll
    for (int gt = 0; gt < 4; ++gt) {
      acc[gt] = (f32x4){biasv[gt], biasv[gt], biasv[gt], biasv[gt]};
      acc[gt] = __builtin_amdgcn_mfma_f32_16x16x32_bf16(xa[0], wih[gt][0], acc[gt], 0, 0, 0);
      acc[gt] = __builtin_amdgcn_mfma_f32_16x16x32_bf16(xa[1], wih[gt][1], acc[gt], 0, 0, 0);
      acc[gt] = __builtin_amdgcn_mfma_f32_16x16x32_bf16(xa[2], wih[gt][2], acc[gt], 0, 0, 0);
      acc[gt] = __builtin_amdgcn_mfma_f32_16x16x32_bf16(xa[3], wih[gt][3], acc[gt], 0, 0, 0);
      acc[gt] = __builtin_amdgcn_mfma_f32_16x16x32_bf16(xa[4], wih[gt][4], acc[gt], 0, 0, 0);
      acc[gt] = __builtin_amdgcn_mfma_f32_16x16x32_bf16(xa[5], wih[gt][5], acc[gt], 0, 0, 0);
      acc[gt] = __builtin_amdgcn_mfma_f32_16x16x32_bf16(xa[6], wih[gt][6], acc[gt], 0, 0, 0);
      acc[gt] = __builtin_amdgcn_mfma_f32_16x16x32_bf16(xa[7], wih[gt][7], acc[gt], 0, 0, 0);
    }

    if (s + 1 < TT) {
      const int tn = dir ? (TT - 2 - s) : (s + 1);
      const ushort* p = xbf + ((size_t)lo * TT + tn) * 256 + hi * 8;
#pragma unroll
      for (int kt = 0; kt < 8; ++kt) xn[kt] = *(const uint4*)(p + kt * 32);
    }

    if (s > 0) {
      const ull* bp = hst + (s & 1) * 2048 + hi * 64 + lo;
      const ull* cp = coefD + (size_t)s * 16 + b0;
      const uint32 su = (uint32)s;
      while (true) {
        uint32 bad = 0;
#pragma unroll
        for (int kt = 0; kt < 8; ++kt) {
          ull w0 = __hip_atomic_load(bp + kt * 256 +  0, __ATOMIC_RELAXED, __HIP_MEMORY_SCOPE_AGENT);
          ull w1 = __hip_atomic_load(bp + kt * 256 + 16, __ATOMIC_RELAXED, __HIP_MEMORY_SCOPE_AGENT);
          ull w2 = __hip_atomic_load(bp + kt * 256 + 32, __ATOMIC_RELAXED, __HIP_MEMORY_SCOPE_AGENT);
          ull w3 = __hip_atomic_load(bp + kt * 256 + 48, __ATOMIC_RELAXED, __HIP_MEMORY_SCOPE_AGENT);
          union { bf16x8 v; uint32 d[4]; } t;
          t.d[0] = (uint32)w0; t.d[1] = (uint32)w1; t.d[2] = (uint32)w2; t.d[3] = (uint32)w3;
          af[kt] = t.v;
          bad |= ((uint32)(w0 >> 32)) ^ su; bad |= ((uint32)(w1 >> 32)) ^ su;
          bad |= ((uint32)(w2 >> 32)) ^ su; bad |= ((uint32)(w3 >> 32)) ^ su;
        }
        if (MODE == 1) {
          ull c0 = __hip_atomic_load(cp + 0, __ATOMIC_RELAXED, __HIP_MEMORY_SCOPE_AGENT);
          ull c1 = __hip_atomic_load(cp + 1, __ATOMIC_RELAXED, __HIP_MEMORY_SCOPE_AGENT);
          ull c2 = __hip_atomic_load(cp + 2, __ATOMIC_RELAXED, __HIP_MEMORY_SCOPE_AGENT);
          ull c3 = __hip_atomic_load(cp + 3, __ATOMIC_RELAXED, __HIP_MEMORY_SCOPE_AGENT);
          bad |= ((uint32)(c0 >> 32)) ^ (su + 1); bad |= ((uint32)(c1 >> 32)) ^ (su + 1);
          bad |= ((uint32)(c2 >> 32)) ^ (su + 1); bad |= ((uint32)(c3 >> 32)) ^ (su + 1);
          co[0] = __uint_as_float((uint32)c0); co[1] = __uint_as_float((uint32)c1);
          co[2] = __uint_as_float((uint32)c2); co[3] = __uint_as_float((uint32)c3);
        }
        if (__all(bad == 0)) break;
        __builtin_amdgcn_s_sleep(1);
      }
#pragma unroll
      for (int gt = 0; gt < 4; ++gt) {
        acc[gt] = __builtin_amdgcn_mfma_f32_16x16x32_bf16(af[0], whh[gt][0], acc[gt], 0, 0, 0);
        acc[gt] = __builtin_amdgcn_mfma_f32_16x16x32_bf16(af[1], whh[gt][1], acc[gt], 0, 0, 0);
        acc[gt] = __builtin_amdgcn_mfma_f32_16x16x32_bf16(af[2], whh[gt][2], acc[gt], 0, 0, 0);
        acc[gt] = __builtin_amdgcn_mfma_f32_16x16x32_bf16(af[3], whh[gt][3], acc[gt], 0, 0, 0);
        acc[gt] = __builtin_amdgcn_mfma_f32_16x16x32_bf16(af[4], whh[gt][4], acc[gt], 0, 0, 0);
        acc[gt] = __builtin_amdgcn_mfma_f32_16x16x32_bf16(af[5], whh[gt][5], acc[gt], 0, 0, 0);
        acc[gt] = __builtin_amdgcn_mfma_f32_16x16x32_bf16(af[6], whh[gt][6], acc[gt], 0, 0, 0);
        acc[gt] = __builtin_amdgcn_mfma_f32_16x16x32_bf16(af[7], whh[gt][7], acc[gt], 0, 0, 0);
      }
    }

#pragma unroll
    for (int r = 0; r < 4; ++r) {
      float gi = acc[0][r];
      float gf = acc[1][r];
      float gg = acc[2][r];
      float go = acc[3][r];
      float cn = sigm(gf) * cprev[r] + sigm(gi) * tanh_fast(gg);
      float hn = sigm(go) * tanh_fast(cn) + co[r] * hprev[r];
      cprev[r] = cn; hprev[r] = hn;
    }

    {
      ull* so = hst + ((s + 1) & 1) * 2048 + (size_t)(w * 32 + wv * 8 + (lo >> 1)) * 16 + b0;
      const ull tg = ((ull)(uint32)(s + 1)) << 32;
#pragma unroll
      for (int r = 0; r < 4; ++r) {
        uint32 h16 = f2bf(hprev[r]);
        uint32 p16 = (uint32)__shfl_xor((int)h16, 1);
        if (!(lo & 1))
          __hip_atomic_store(so + r, (ull)(h16 | (p16 << 16)) | tg,
                             __ATOMIC_RELAXED, __HIP_MEMORY_SCOPE_AGENT);
      }
      asm volatile("" ::: "memory");
    }

    if (MODE == 0 && s > 0 && w == 0 && wv == 0) {
      float part = 0.f;
#pragma unroll
      for (int kt = 0; kt < 8; ++kt) {
        const float* cwp = &ldsCW[kt * 32 + hi * 8];
        f32x4 c0 = *(const f32x4*)cwp;
        f32x4 c1 = *(const f32x4*)(cwp + 4);
#pragma unroll
        for (int j = 0; j < 4; ++j) {
          part += c0[j] * bf2f((ushort)af[kt][j]);
          part += c1[j] * bf2f((ushort)af[kt][4 + j]);
        }
      }
      part += __shfl_xor(part, 16);
      part += __shfl_xor(part, 32);
      if (hi == 0) {
        uint32 pb = __float_as_uint(0.9f * sigm(part + cbias));
        __hip_atomic_store(coefD + (size_t)(s - 1) * 16 + lo, (((ull)(uint32)s) << 32) | pb,
                           __ATOMIC_RELAXED, __HIP_MEMORY_SCOPE_AGENT);
      }
      asm volatile("" ::: "memory");
    }

    if (MODE == 1) {
      const int t_nat = dir ? (TT - 1 - s) : s;
#pragma unroll
      for (int r = 0; r < 4; ++r)
        outBf[((size_t)(b0 + r) * TT + t_nat) * 512 + dir * 256 + unit] = f2bf(hprev[r]);
    }
  }

  if (MODE == 0 && w == 0 && wv == 0) {
    const ull* bp = hst + (TT & 1) * 2048 + hi * 64 + lo;
    const uint32 su = (uint32)TT;
    while (true) {
      uint32 bad = 0;
#pragma unroll
      for (int kt = 0; kt < 8; ++kt) {
        ull w0 = __hip_atomic_load(bp + kt * 256 +  0, __ATOMIC_RELAXED, __HIP_MEMORY_SCOPE_AGENT);
        ull w1 = __hip_atomic_load(bp + kt * 256 + 16, __ATOMIC_RELAXED, __HIP_MEMORY_SCOPE_AGENT);
        ull w2 = __hip_atomic_load(bp + kt * 256 + 32, __ATOMIC_RELAXED, __HIP_MEMORY_SCOPE_AGENT);
        ull w3 = __hip_atomic_load(bp + kt * 256 + 48, __ATOMIC_RELAXED, __HIP_MEMORY_SCOPE_AGENT);
        union { bf16x8 v; uint32 d[4]; } t;
        t.d[0] = (uint32)w0; t.d[1] = (uint32)w1; t.d[2] = (uint32)w2; t.d[3] = (uint32)w3;
        af[kt] = t.v;
        bad |= ((uint32)(w0 >> 32)) ^ su; bad |= ((uint32)(w1 >> 32)) ^ su;
        bad |= ((uint32)(w2 >> 32)) ^ su; bad |= ((uint32)(w3 >> 32)) ^ su;
      }
      if (__all(bad == 0)) break;
      __builtin_amdgcn_s_sleep(1);
    }
    float part = 0.f;
#pragma unroll
    for (int kt = 0; kt < 8; ++kt) {
      const float* cwp = &ldsCW[kt * 32 + hi * 8];
      f32x4 c0 = *(const f32x4*)cwp;
      f32x4 c1 = *(const f32x4*)(cwp + 4);
#pragma unroll
      for (int j = 0; j < 4; ++j) {
        part += c0[j] * bf2f((ushort)af[kt][j]);
        part += c1[j] * bf2f((ushort)af[kt][4 + j]);
      }
    }
    part += __shfl_xor(part, 16);
    part += __shfl_xor(part, 32);
    if (hi == 0) {
      uint32 pb = __float_as_uint(0.9f * sigm(part + cbias));
      __hip_atomic_store(coefD + (size_t)(TT - 1) * 16 + lo, (((ull)(uint32)TT) << 32) | pb,
                         __ATOMIC_RELAXED, __HIP_MEMORY_SCOPE_AGENT);
    }
    asm volatile("" ::: "memory");
  }
}

// fused dcg + layer0: 16 blocks (0-7 dcg, 8-15 l0)
__global__ __launch_bounds__(256, 1) void fused_AB(
    const ushort* __restrict__ xbf,
    const float* __restrict__ dWihF, const float* __restrict__ dWihB,
    const float* __restrict__ dWhhF, const float* __restrict__ dWhhB,
    const float* __restrict__ lWihF, const float* __restrict__ lWihB,
    const float* __restrict__ lWhhF, const float* __restrict__ lWhhB,
    const float* __restrict__ biasA, const float* __restrict__ biasB,
    const float* __restrict__ cwF, const float* __restrict__ cwB,
    const float* __restrict__ cbF, const float* __restrict__ cbB,
    ull* __restrict__ coefT, ull* __restrict__ hstA, ull* __restrict__ hstB,
    ushort* __restrict__ xcat)
{
  __shared__ float ldsCW[256];
  const int tid = threadIdx.x;
  const int role = blockIdx.x >> 3;
  const int dir = (blockIdx.x >> 2) & 1, w = blockIdx.x & 3;
  float cbias = 0.f;
  if (role == 0) { ldsCW[tid] = (dir ? cwB : cwF)[tid]; cbias = dir ? cbB[0] : cbF[0]; }
  __syncthreads();
  if (role == 0)
    scan_fly<0>(xbf, dWihF, dWihB, dWhhF, dWhhB, biasA, ldsCW, cbias,
                coefT, hstA, (ushort*)nullptr, dir, w, tid);
  else
    scan_fly<1>(xbf, lWihF, lWihB, lWhhF, lWhhB, biasB, ldsCW, 0.f,
                coefT, hstB, xcat, dir, w, tid);
}

// ---------------- l1 scan v2: 2 blocks/dir, own half via LDS, partner tagged ----------------
// grid = 4 blocks: dir(2) x half(2). 256 thr = 4 waves, 1 wave/SIMD.
// Block owns 128 units (weights 256 VGPR register-resident, static indices).
// Own h half: LDS double-buffer (XOR-swizzled, 1 barrier/step).
// Partner half: tagged 8B words via relaxed agent atomics + s_sleep backoff. Fan-in 1.
__global__ __launch_bounds__(256, 1) void scan_l1(
    const ushort* __restrict__ xp,
    const float* __restrict__ WhhF, const float* __restrict__ WhhB,
    ull* __restrict__ coefT, ull* __restrict__ hst_base,
    float* __restrict__ outF32)
{
  const int tid = threadIdx.x;
  const int lane = tid & 63, wv = tid >> 6;
  const int lo = lane & 15, hi = lane >> 4;
  const int dir = blockIdx.x >> 1, w = blockIdx.x & 1;

  __shared__ __align__(16) ushort ldsH[2][16 * 128];  // [buf][batch][128 local units]

  const ushort* xpD = xp + (size_t)dir * ((size_t)BATCH * TT * 1024);
  const float* Whh = dir ? WhhB : WhhF;
  ull* hst = hst_base + dir * (2 * 2048);
  ull* coefD = coefT + (size_t)dir * TT * 16;

  const int ub = w * 128 + wv * 32;     // wave's unit base; lane units: ub+lo, ub+16+lo
  const int b0 = hi * 4;
  const int sh = (lo & 1) * 16;

  // weights: wfrag[gate][ug][kt], 256 VGPR, all static indices
  bf16x8 wfrag[4][2][8];
#pragma unroll
  for (int gt = 0; gt < 4; ++gt) {
#pragma unroll
    for (int ug = 0; ug < 2; ++ug) {
      const float* wrow = Whh + (size_t)(gt * HID + ub + ug * 16 + lo) * HID;
#pragma unroll
      for (int kt = 0; kt < 8; ++kt) {
        bf16x8 f;
#pragma unroll
        for (int j = 0; j < 8; ++j) f[j] = (short)f2bf(wrow[kt * 32 + hi * 8 + j]);
        wfrag[gt][ug][kt] = f;
      }
    }
  }

  float hprev[2][4] = {}, cprev[2][4] = {};
  float co[4] = {0, 0, 0, 0};
  uint4 xq[2][4];
  {
    const int t0 = dir ? (TT - 1) : 0;
#pragma unroll
    for (int ug = 0; ug < 2; ++ug) {
      const size_t pofs = (size_t)((ub + ug * 16 + lo) >> 1) * 8;
#pragma unroll
      for (int r = 0; r < 4; ++r)
        xq[ug][r] = *(const uint4*)(xpD + ((size_t)(b0 + r) * TT + t0) * 1024 + pofs);
    }
  }

  for (int s = 0; s < TT; ++s) {
    f32x4 acc[4][2] = {};
    if (s > 0) {
      bf16x8 af0, af1, af2, af3, af4, af5, af6, af7;
      const char* lb = (const char*)ldsH + (s & 1) * 4096 + lo * 256;
      const int lx = (lo & 7) << 4;
      const ull* bp = hst + (s & 1) * 2048 + hi * 64 + lo;
      const uint32 su = (uint32)s;

#define LDK(KT, A) { \
        ull w0 = __hip_atomic_load(bp + KT * 256 +  0, __ATOMIC_RELAXED, __HIP_MEMORY_SCOPE_AGENT); \
        ull w1 = __hip_atomic_load(bp + KT * 256 + 16, __ATOMIC_RELAXED, __HIP_MEMORY_SCOPE_AGENT); \
        ull w2 = __hip_atomic_load(bp + KT * 256 + 32, __ATOMIC_RELAXED, __HIP_MEMORY_SCOPE_AGENT); \
        ull w3 = __hip_atomic_load(bp + KT * 256 + 48, __ATOMIC_RELAXED, __HIP_MEMORY_SCOPE_AGENT); \
        union { bf16x8 v; uint32 d[4]; } t; \
        t.d[0] = (uint32)w0; t.d[1] = (uint32)w1; t.d[2] = (uint32)w2; t.d[3] = (uint32)w3; \
        A = t.v; \
        bad |= ((uint32)(w0 >> 32)) ^ su; bad |= ((uint32)(w1 >> 32)) ^ su; \
        bad |= ((uint32)(w2 >> 32)) ^ su; bad |= ((uint32)(w3 >> 32)) ^ su; }

      if (w == 0) {
        af0 = *(const bf16x8*)(lb + ((0 * 64 + hi * 16) ^ lx));
        af1 = *(const bf16x8*)(lb + ((1 * 64 + hi * 16) ^ lx));
        af2 = *(const bf16x8*)(lb + ((2 * 64 + hi * 16) ^ lx));
        af3 = *(const bf16x8*)(lb + ((3 * 64 + hi * 16) ^ lx));
        while (true) {
          uint32 bad = 0;
          LDK(4, af4) LDK(5, af5) LDK(6, af6) LDK(7, af7)
          if (__all(bad == 0)) break;
          __builtin_amdgcn_s_sleep(1);
        }
      } else {
        af4 = *(const bf16x8*)(lb + ((0 * 64 + hi * 16) ^ lx));
        af5 = *(const bf16x8*)(lb + ((1 * 64 + hi * 16) ^ lx));
        af6 = *(const bf16x8*)(lb + ((2 * 64 + hi * 16) ^ lx));
        af7 = *(const bf16x8*)(lb + ((3 * 64 + hi * 16) ^ lx));
        while (true) {
          uint32 bad = 0;
          LDK(0, af0) LDK(1, af1) LDK(2, af2) LDK(3, af3)
          if (__all(bad == 0)) break;
          __builtin_amdgcn_s_sleep(1);
        }
      }
#undef LDK

#pragma unroll
      for (int gt = 0; gt < 4; ++gt) {
#pragma unroll
        for (int ug = 0; ug < 2; ++ug) {
          acc[gt][ug] = __builtin_amdgcn_mfma_f32_16x16x32_bf16(af0, wfrag[gt][ug][0], acc[gt][ug], 0, 0, 0);
          acc[gt][ug] = __builtin_amdgcn_mfma_f32_16x16x32_bf16(af1, wfrag[gt][ug][1], acc[gt][ug], 0, 0, 0);
          acc[gt][ug] = __builtin_amdgcn_mfma_f32_16x16x32_bf16(af2, wfrag[gt][ug][2], acc[gt][ug], 0, 0, 0);
          acc[gt][ug] = __builtin_amdgcn_mfma_f32_16x16x32_bf16(af3, wfrag[gt][ug][3], acc[gt][ug], 0, 0, 0);
          acc[gt][ug] = __builtin_amdgcn_mfma_f32_16x16x32_bf16(af4, wfrag[gt][ug][4], acc[gt][ug], 0, 0, 0);
          acc[gt][ug] = __builtin_amdgcn_mfma_f32_16x16x32_bf16(af5, wfrag[gt][ug][5], acc[gt][ug], 0, 0, 0);
          acc[gt][ug] = __builtin_amdgcn_mfma_f32_16x16x32_bf16(af6, wfrag[gt][ug][6], acc[gt][ug], 0, 0, 0);
          acc[gt][ug] = __builtin_amdgcn_mfma_f32_16x16x32_bf16(af7, wfrag[gt][ug][7], acc[gt][ug], 0, 0, 0);
        }
      }
    }

    // gates
#pragma unroll
    for (int ug = 0; ug < 2; ++ug) {
#pragma unroll
      for (int r = 0; r < 4; ++r) {
        uint4 q = xq[ug][r];
        float gi = acc[0][ug][r] + bf2f((ushort)(q.x >> sh));
        float gf = acc[1][ug][r] + bf2f((ushort)(q.y >> sh));
        float gg = acc[2][ug][r] + bf2f((ushort)(q.z >> sh));
        float go = acc[3][ug][r] + bf2f((ushort)(q.w >> sh));
        float cn = sigm(gf) * cprev[ug][r] + sigm(gi) * tanh_fast(gg);
        float hn = sigm(go) * tanh_fast(cn) + co[r] * hprev[ug][r];
        cprev[ug][r] = cn; hprev[ug][r] = hn;
      }
    }

    // publish h_s: global tagged (for partner) + LDS (own block)
    {
      const int nb = (s + 1) & 1;
      const ull tg = ((ull)(uint32)(s + 1)) << 32;
#pragma unroll
      for (int ug = 0; ug < 2; ++ug) {
#pragma unroll
        for (int r = 0; r < 4; ++r) {
          uint32 h16 = f2bf(hprev[ug][r]);
          uint32 p16 = (uint32)__shfl_xor((int)h16, 1);
          if (!(lo & 1)) {
            uint32 pk = h16 | (p16 << 16);
            int p = (ub + ug * 16 + lo) >> 1;
            __hip_atomic_store(hst + nb * 2048 + (size_t)p * 16 + (b0 + r),
                               (ull)pk | tg, __ATOMIC_RELAXED, __HIP_MEMORY_SCOPE_AGENT);
            int ulocal = wv * 32 + ug * 16 + lo;
            int bo = nb * 4096 + (b0 + r) * 256 + ulocal * 2;
            bo ^= (((b0 + r) & 7) << 4);
            *(uint32*)((char*)ldsH + bo) = pk;
          }
        }
      }
      asm volatile("" ::: "memory");
    }
    __syncthreads();

    // output fp32
    {
      const int t_nat = dir ? (TT - 1 - s) : s;
#pragma unroll
      for (int ug = 0; ug < 2; ++ug)
#pragma unroll
        for (int r = 0; r < 4; ++r)
          outF32[((size_t)(b0 + r) * TT + t_nat) * 512 + dir * 256 + ub + ug * 16 + lo] = hprev[ug][r];
    }

    // prefetch next xq + coeff (plain loads; coefT fully written by fused phase)
    if (s + 1 < TT) {
      const int tn = dir ? (TT - 2 - s) : (s + 1);
#pragma unroll
      for (int ug = 0; ug < 2; ++ug) {
        const size_t pofs = (size_t)((ub + ug * 16 + lo) >> 1) * 8;
#pragma unroll
        for (int r = 0; r < 4; ++r)
          xq[ug][r] = *(const uint4*)(xpD + ((size_t)(b0 + r) * TT + tn) * 1024 + pofs);
      }
      co[0] = __uint_as_float((uint32)coefD[(size_t)(s + 1) * 16 + b0 + 0]);
      co[1] = __uint_as_float((uint32)coefD[(size_t)(s + 1) * 16 + b0 + 1]);
      co[2] = __uint_as_float((uint32)coefD[(size_t)(s + 1) * 16 + b0 + 2]);
      co[3] = __uint_as_float((uint32)coefD[(size_t)(s + 1) * 16 + b0 + 3]);
    }
  }
}

extern "C" void kernel_launch(void* const* d_in, const int* in_sizes, int n_in,
                              void* d_out, int out_size, void* d_ws, size_t ws_size,
                              hipStream_t stream)
{
  const float* x       = (const float*)d_in[0];
  const float* dWih_f  = (const float*)d_in[1];
  const float* dWhh_f  = (const float*)d_in[2];
  const float* dbih_f  = (const float*)d_in[3];
  const float* dbhh_f  = (const float*)d_in[4];
  const float* dWih_b  = (const float*)d_in[5];
  const float* dWhh_b  = (const float*)d_in[6];
  const float* dbih_b  = (const float*)d_in[7];
  const float* dbhh_b  = (const float*)d_in[8];
  const float* l0Wih_f = (const float*)d_in[9];
  const float* l0Whh_f = (const float*)d_in[10];
  const float* l0bih_f = (const float*)d_in[11];
  const float* l0bhh_f = (const float*)d_in[12];
  const float* l0Wih_b = (const float*)d_in[13];
  const float* l0Whh_b = (const float*)d_in[14];
  const float* l0bih_b = (const float*)d_in[15];
  const float* l0bhh_b = (const float*)d_in[16];
  const float* l1Wih_f = (const float*)d_in[17];
  const float* l1Whh_f = (const float*)d_in[18];
  const float* l1bih_f = (const float*)d_in[19];
  const float* l1bhh_f = (const float*)d_in[20];
  const float* l1Wih_b = (const float*)d_in[21];
  const float* l1Whh_b = (const float*)d_in[22];
  const float* l1bih_b = (const float*)d_in[23];
  const float* l1bhh_b = (const float*)d_in[24];
  const float* cw_f    = (const float*)d_in[25];
  const float* cbi_f   = (const float*)d_in[26];
  const float* cw_b    = (const float*)d_in[27];
  const float* cbi_b   = (const float*)d_in[28];

  char* ws = (char*)d_ws;
  constexpr size_t OFF_XP   = 0;
  constexpr size_t SZ_XP    = 2ull * BATCH * TT * 1024 * 2;   // 128 MB (l1 only)
  constexpr size_t OFF_XCAT = OFF_XP + SZ_XP;
  constexpr size_t SZ_XCAT  = (size_t)BATCH * TT * 512 * 2;   // 32 MB
  constexpr size_t OFF_XBF  = OFF_XCAT + SZ_XCAT;
  constexpr size_t SZ_XBF   = (size_t)BATCH * TT * 256 * 2;   // 16 MB
  constexpr size_t OFF_WC   = OFF_XBF + SZ_XBF;
  constexpr size_t SZ_WC    = 2048ull * 512 * 2;              // 2 MB
  constexpr size_t OFF_BA   = OFF_WC + SZ_WC;
  constexpr size_t OFF_BB   = OFF_BA + 8192;
  constexpr size_t OFF_BC   = OFF_BB + 8192;
  constexpr size_t OFF_CO   = OFF_BC + 8192;
  constexpr size_t SZ_CO    = 2ull * TT * 16 * 8;             // tagged coeff
  constexpr size_t OFF_HST  = OFF_CO + SZ_CO;
  constexpr size_t SZ_HST   = 3ull * 2 * 2 * 2048 * 8;
  constexpr size_t NEED     = OFF_HST + SZ_HST;
  if (ws_size < NEED) return;

  ushort* xp    = (ushort*)(ws + OFF_XP);
  ushort* xcat  = (ushort*)(ws + OFF_XCAT);
  ushort* xbf   = (ushort*)(ws + OFF_XBF);
  ushort* wC    = (ushort*)(ws + OFF_WC);
  float*  biasA = (float*)(ws + OFF_BA);
  float*  biasB = (float*)(ws + OFF_BB);
  float*  biasC = (float*)(ws + OFF_BC);
  ull*    coefT = (ull*)(ws + OFF_CO);
  ull*    hst   = (ull*)(ws + OFF_HST);

  prep_kernel<<<512, 256, 0, stream>>>(
      x, l1Wih_f, l1Wih_b,
      dbih_f, dbhh_f, dbih_b, dbhh_b, l0bih_f, l0bhh_f, l0bih_b, l0bhh_b,
      l1bih_f, l1bhh_f, l1bih_b, l1bhh_b,
      xbf, wC, biasA, biasB, biasC);
  hipMemsetAsync(ws + OFF_CO, 0, SZ_CO + SZ_HST, stream);

  const size_t HSTR = 2 * 2 * 2048;

  fused_AB<<<16, 256, 0, stream>>>(xbf,
                                   dWih_f, dWih_b, dWhh_f, dWhh_b,
                                   l0Wih_f, l0Wih_b, l0Whh_f, l0Whh_b,
                                   biasA, biasB, cw_f, cw_b, cbi_f, cbi_b,
                                   coefT, hst + 0 * HSTR, hst + 1 * HSTR, xcat);
  gemm_xp<<<dim3(16, 256), 256, 0, stream>>>(xcat, wC, 512, biasC, xp);
  scan_l1<<<4, 256, 0, stream>>>(xp, l1Whh_f, l1Whh_b, coefT, hst + 2 * HSTR, (float*)d_out);
}